// Round 4
// baseline (179.321 us; speedup 1.0000x reference)
//
#include <hip/hip_runtime.h>
#include <hip/hip_bf16.h>

#define NUM_CLASSES 7
#define BLOCK 256
#define NBLOCKS 2048

// Register-tiled main kernel: each thread owns 4 consecutive rows =
// 28 floats = 7 aligned float4 (112 B) + one int4 of targets. No LDS,
// no barriers, all loads 16 B/lane vector loads, static reg indexing.
__global__ __launch_bounds__(BLOCK) void pom_main(const float* __restrict__ logits,
                                                  const int* __restrict__ targets,
                                                  double* __restrict__ partials,
                                                  int B) {
    const int tid = blockIdx.x * BLOCK + threadIdx.x;
    const int nth = gridDim.x * BLOCK;
    const int nChunks = B >> 2;                 // full 4-row chunks
    const float4* __restrict__ g4 = (const float4*)logits;
    const int4*   __restrict__ t4 = (const int4*)targets;

    float acc = 0.0f;

    for (int c = tid; c < nChunks; c += nth) {
        // 7 x float4 = rows 4c .. 4c+3 (28 consecutive floats, 16B-aligned:
        // chunk byte offset = c*112, 112 % 16 == 0).
        float4 v[7];
        const float4* p = g4 + (long long)c * 7;
        #pragma unroll
        for (int j = 0; j < 7; ++j) v[j] = p[j];
        const int4 tgv = t4[c];
        const int tgs[4] = {tgv.x, tgv.y, tgv.z, tgv.w};
        const float* f = (const float*)v;       // static indices after unroll

        #pragma unroll
        for (int r = 0; r < 4; ++r) {
            const int tg = tgs[r];
            float lv[7];
            #pragma unroll
            for (int i = 0; i < NUM_CLASSES; ++i) lv[i] = f[r * 7 + i];

            float m = lv[0];
            #pragma unroll
            for (int i = 1; i < NUM_CLASSES; ++i) m = fmaxf(m, lv[i]);

            float s = 0.0f, w = 0.0f;
            #pragma unroll
            for (int i = 0; i < NUM_CLASSES; ++i) {
                float e = __expf(lv[i] - m);
                s += e;
                bool in = (i >= tg - 1) && (i <= tg + 1);   // fully predicated
                w += in ? e : 0.0f;
            }
            acc += -__logf(w / s + 1e-10f);
        }
    }

    // Tail rows (B % 4 != 0 — not hit for B = 4M, kept for correctness).
    const int tailStart = nChunks << 2;
    for (int row = tailStart + tid; row < B; row += nth) {
        const float* l = logits + (long long)row * NUM_CLASSES;
        const int tg = targets[row];
        float lv[7];
        #pragma unroll
        for (int i = 0; i < NUM_CLASSES; ++i) lv[i] = l[i];
        float m = lv[0];
        #pragma unroll
        for (int i = 1; i < NUM_CLASSES; ++i) m = fmaxf(m, lv[i]);
        float s = 0.0f, w = 0.0f;
        #pragma unroll
        for (int i = 0; i < NUM_CLASSES; ++i) {
            float e = __expf(lv[i] - m);
            s += e;
            bool in = (i >= tg - 1) && (i <= tg + 1);
            w += in ? e : 0.0f;
        }
        acc += -__logf(w / s + 1e-10f);
    }

    // Block reduction in double (deterministic).
    double d = (double)acc;
    #pragma unroll
    for (int off = 32; off > 0; off >>= 1) d += __shfl_down(d, off, 64);

    __shared__ double wsum[BLOCK / 64];
    if ((threadIdx.x & 63) == 0) wsum[threadIdx.x >> 6] = d;
    __syncthreads();
    if (threadIdx.x == 0) {
        double blk = 0.0;
        #pragma unroll
        for (int i = 0; i < BLOCK / 64; ++i) blk += wsum[i];
        partials[blockIdx.x] = blk;
    }
}

// Finalize: reduce per-block partials, write mean as f32.
__global__ __launch_bounds__(BLOCK) void pom_finalize(const double* __restrict__ partials,
                                                      int n, float* __restrict__ out,
                                                      double invB) {
    const int tid = threadIdx.x;
    double d = 0.0;
    for (int i = tid; i < n; i += BLOCK) d += partials[i];
    #pragma unroll
    for (int off = 32; off > 0; off >>= 1) d += __shfl_down(d, off, 64);

    __shared__ double wsum[BLOCK / 64];
    if ((tid & 63) == 0) wsum[tid >> 6] = d;
    __syncthreads();
    if (tid == 0) {
        double s = 0.0;
        #pragma unroll
        for (int i = 0; i < BLOCK / 64; ++i) s += wsum[i];
        out[0] = (float)(s * invB);
    }
}

extern "C" void kernel_launch(void* const* d_in, const int* in_sizes, int n_in,
                              void* d_out, int out_size, void* d_ws, size_t ws_size,
                              hipStream_t stream) {
    const float* logits  = (const float*)d_in[0];
    const int*   targets = (const int*)d_in[1];
    const int B = in_sizes[1];              // targets count = batch
    float* out = (float*)d_out;
    double* partials = (double*)d_ws;       // NBLOCKS doubles = 16 KiB scratch

    pom_main<<<NBLOCKS, BLOCK, 0, stream>>>(logits, targets, partials, B);
    pom_finalize<<<1, BLOCK, 0, stream>>>(partials, NBLOCKS, out, 1.0 / (double)B);
}